// Round 1
// baseline (965.672 us; speedup 1.0000x reference)
//
#include <hip/hip_runtime.h>
#include <math.h>

#define B_SZ 128
#define D_SZ 128

// ---------------------------------------------------------------------------
// up2_combine<L>: out[b,m,c] = xh[b,m,c] + sign * up2(xl)[b,m,c]
//   up2 = frequency-domain 2x upsample (rfft -> zero-pad -> irfft -> *1/2):
//   even m=2t : up = xl[t]/4 + (-1)^t * S_alt/(4L),  S_alt = sum_n (-1)^n xl[n]
//   odd  m=2t+1: up = (1/4L) * sum_e xl[(t-e) mod L] * s(e),
//                s(e) = (-1)^e * cot(pi*(2e+1)/(2L))
// Used for both dec residuals (sign=-1, xh=original level, out=ws) and
// the mix up-add (sign=+1, xh==out, in-place per-element RMW).
// Block: 256 threads handles (b, 32-channel tile), all 2L output rows.
// ---------------------------------------------------------------------------
template<int L>
__global__ __launch_bounds__(256) void up2_combine(
    const float* __restrict__ xl,   // (B, L, D)
    const float* __restrict__ xh,   // (B, 2L, D)
    float* __restrict__ out,        // (B, 2L, D)
    float sign)
{
    const int b   = blockIdx.x;
    const int c0  = blockIdx.y * 32;
    const int tid = threadIdx.x;

    __shared__ float xs[L][32];   // xl tile: row stride 32 -> 2-way bank alias (free)
    __shared__ float stab[L];     // cot kernel taps
    __shared__ float salt[32];    // alternating sums per channel

    for (int idx = tid; idx < L * 32; idx += 256) {
        int n = idx >> 5, c = idx & 31;
        xs[n][c] = xl[((size_t)b * L + n) * D_SZ + c0 + c];
    }
    for (int e = tid; e < L; e += 256) {
        double th = M_PI * (2.0 * e + 1.0) / (2.0 * L);
        double ct = cos(th) / sin(th);
        stab[e] = (float)((e & 1) ? -ct : ct);
    }
    __syncthreads();
    if (tid < 32) {
        float s = 0.f;
        for (int n = 0; n < L; ++n) s += (n & 1) ? -xs[n][tid] : xs[n][tid];
        salt[tid] = s;
    }
    __syncthreads();

    const float inv4L = 1.0f / (4.0f * (float)L);
    const int c = tid & 31;
    const int r = tid >> 5;   // 0..7

    // even outputs (cheap)
    for (int t = r; t < L; t += 8) {
        float up = 0.25f * xs[t][c] + ((t & 1) ? -salt[c] : salt[c]) * inv4L;
        size_t idx = ((size_t)b * (2 * L) + 2 * t) * D_SZ + c0 + c;
        out[idx] = xh[idx] + sign * up;
    }
    // odd outputs (L-tap circular conv)
    for (int t = r; t < L; t += 8) {
        float acc = 0.f;
        int n = t;
        for (int e = 0; e < L; ++e) {
            acc += xs[n][c] * stab[e];
            n = (n == 0) ? (L - 1) : (n - 1);
        }
        float up = acc * inv4L;
        size_t idx = ((size_t)b * (2 * L) + 2 * t + 1) * D_SZ + c0 + c;
        out[idx] = xh[idx] + sign * up;
    }
}

// ---------------------------------------------------------------------------
// mkan_kernel<L,DEG1,NT>: out[b,n,o] = sum_{i,d} T_d(tanh(tanh(x[b,n,i]))) *
//   coeffs[i,o,d]  +  depthwise conv3 (zero-padded) of x with w[o,0..2].
// Chebyshev identity: cos(d*arccos(u)) = T_d(u) -> pure FMA recurrence.
// Block: 256 threads handles (b, NT-row tile), all 128 output channels.
// ---------------------------------------------------------------------------
template<int L, int DEG1, int NT>
__global__ __launch_bounds__(256) void mkan_kernel(
    const float* __restrict__ x,      // (B, L, 128)
    const float* __restrict__ coeffs, // (128, 128, DEG1)
    const float* __restrict__ w,      // (128, 3)
    float* __restrict__ out)          // (B, L, 128)
{
    const int b   = blockIdx.x;
    const int n0  = blockIdx.y * NT;
    const int tid = threadIdx.x;

    __shared__ float xr[NT + 2][D_SZ];  // raw rows n0-1 .. n0+NT (zero-padded)
    __shared__ float tt[NT][D_SZ];      // tanh(tanh(x)) rows n0 .. n0+NT-1

    for (int idx = tid; idx < (NT + 2) * D_SZ; idx += 256) {
        int rr = idx >> 7, c = idx & 127;
        int n = n0 - 1 + rr;
        float v = 0.f;
        if (n >= 0 && n < L) v = x[((size_t)b * L + n) * D_SZ + c];
        xr[rr][c] = v;
    }
    __syncthreads();
    for (int idx = tid; idx < NT * D_SZ; idx += 256) {
        int nl = idx >> 7, c = idx & 127;
        tt[nl][c] = tanhf(tanhf(xr[nl + 1][c]));
    }
    __syncthreads();

    const int o  = tid & 127;
    const int ng = tid >> 7;            // 0 or 1
    const float w0 = w[o * 3 + 0], w1 = w[o * 3 + 1], w2 = w[o * 3 + 2];

    float acc[NT / 2];
    #pragma unroll
    for (int j = 0; j < NT / 2; ++j) {
        int nl = ng + 2 * j;            // xr row nl == global n-1 for this output
        acc[j] = xr[nl][o] * w0 + xr[nl + 1][o] * w1 + xr[nl + 2][o] * w2;
    }

    for (int i = 0; i < D_SZ; ++i) {
        const float* cb = coeffs + ((size_t)i * D_SZ + o) * DEG1;
        float cd[DEG1];
        #pragma unroll
        for (int d = 0; d < DEG1; ++d) cd[d] = cb[d];
        #pragma unroll
        for (int j = 0; j < NT / 2; ++j) {
            float t  = tt[ng + 2 * j][i];   // wave-uniform -> LDS broadcast
            float s  = fmaf(cd[1], t, cd[0]);
            float tp = 1.f, tc = t, t2 = t + t;
            #pragma unroll
            for (int d = 2; d < DEG1; ++d) {
                float tn = fmaf(t2, tc, -tp);
                s = fmaf(cd[d], tn, s);
                tp = tc; tc = tn;
            }
            acc[j] += s;
        }
    }

    #pragma unroll
    for (int j = 0; j < NT / 2; ++j) {
        int n = n0 + ng + 2 * j;
        out[((size_t)b * L + n) * D_SZ + o] = acc[j];
    }
}

extern "C" void kernel_launch(void* const* d_in, const int* in_sizes, int n_in,
                              void* d_out, int out_size, void* d_ws, size_t ws_size,
                              hipStream_t stream) {
    const float* x0 = (const float*)d_in[0];   // (128, 512, 128)
    const float* x1 = (const float*)d_in[1];   // (128, 256, 128)
    const float* x2 = (const float*)d_in[2];   // (128, 128, 128)
    const float* x3 = (const float*)d_in[3];   // (128,  64, 128)
    const float* c0 = (const float*)d_in[4];   // (128,128,2)
    const float* w0 = (const float*)d_in[5];
    const float* c1 = (const float*)d_in[6];   // (128,128,3)
    const float* w1 = (const float*)d_in[7];
    const float* c2 = (const float*)d_in[8];   // (128,128,4)
    const float* w2 = (const float*)d_in[9];
    const float* c3 = (const float*)d_in[10];  // (128,128,5)
    const float* w3 = (const float*)d_in[11];
    float* out = (float*)d_out;

    // workspace: dec residuals (58.7 MB total)
    float* d0 = (float*)d_ws;                        // (128,512,128)
    float* d1 = d0 + (size_t)B_SZ * 512 * D_SZ;      // (128,256,128)
    float* d2 = d1 + (size_t)B_SZ * 256 * D_SZ;      // (128,128,128)

    // outputs concatenated in return order: (m3, m2, m1, m0)
    float* m3 = out;                                 // (128,512,128)
    float* m2 = m3 + (size_t)B_SZ * 512 * D_SZ;      // (128,256,128)
    float* m1 = m2 + (size_t)B_SZ * 256 * D_SZ;      // (128,128,128)
    float* m0 = m1 + (size_t)B_SZ * 128 * D_SZ;      // (128, 64,128)

    dim3 blk(256);

    // --- decomposition: d_i = x_i - up2(x_{i+1})  (independent) ---
    up2_combine<64 ><<<dim3(B_SZ, 4), blk, 0, stream>>>(x3, x2, d2, -1.f);
    up2_combine<128><<<dim3(B_SZ, 4), blk, 0, stream>>>(x2, x1, d1, -1.f);
    up2_combine<256><<<dim3(B_SZ, 4), blk, 0, stream>>>(x1, x0, d0, -1.f);

    // --- mixing chain ---
    mkan_kernel<64, 2, 32><<<dim3(B_SZ, 64 / 32), blk, 0, stream>>>(x3, c0, w0, m0);

    mkan_kernel<128, 3, 32><<<dim3(B_SZ, 128 / 32), blk, 0, stream>>>(d2, c1, w1, m1);
    up2_combine<64 ><<<dim3(B_SZ, 4), blk, 0, stream>>>(m0, m1, m1, 1.f);

    mkan_kernel<256, 4, 32><<<dim3(B_SZ, 256 / 32), blk, 0, stream>>>(d1, c2, w2, m2);
    up2_combine<128><<<dim3(B_SZ, 4), blk, 0, stream>>>(m1, m2, m2, 1.f);

    mkan_kernel<512, 5, 32><<<dim3(B_SZ, 512 / 32), blk, 0, stream>>>(d0, c3, w3, m3);
    up2_combine<256><<<dim3(B_SZ, 4), blk, 0, stream>>>(m2, m3, m3, 1.f);
}

// Round 2
// 623.566 us; speedup vs baseline: 1.5486x; 1.5486x over previous
//
#include <hip/hip_runtime.h>
#include <math.h>

#define B_SZ 128
#define D_SZ 128

// ---------------------------------------------------------------------------
// up2_combine<L>: out[b,m,c] = xh[b,m,c] + sign * up2(xl)[b,m,c]
//   up2 = frequency-domain 2x upsample (rfft -> zero-pad -> irfft -> *1/2):
//   even m=2t : up = xl[t]/4 + (-1)^t * S_alt/(4L),  S_alt = sum_n (-1)^n xl[n]
//   odd  m=2t+1: up = (1/4L) * sum_n xl[n] * s((t-n) mod L),
//                s(e) = (-1)^e * cot(pi*(2e+1)/(2L))
//
// R1 rewrite: register-blocked odd conv. Thread owns 16 consecutive t and a
// 24-entry sliding s-window in registers; x streamed in float4 chunks of 8.
// Per chunk: 4 ds_read_b128 + 128 v_fma  -> VALU-bound (was ds_read_b32-bound
// at ~2 LDS issues per FMA = ~200us/call for L=256).
// Block: 256 thr = (c=tid&31 channel, r=tid>>5 t-group). Grid (B, 4).
// ---------------------------------------------------------------------------
template<int L>
__global__ __launch_bounds__(256) void up2_combine(
    const float* __restrict__ xl,   // (B, L, D)
    const float* __restrict__ xh,   // (B, 2L, D)
    float* __restrict__ out,        // (B, 2L, D)
    float sign)
{
    const int b   = blockIdx.x;
    const int c0  = blockIdx.y * 32;
    const int tid = threadIdx.x;
    const int c   = tid & 31;
    const int r   = tid >> 5;   // 0..7

    __shared__ float xst[32][L + 4];     // xl transposed: xst[c][n]; +4 keeps rows 16B-aligned
    __shared__ float stab_ext[2 * L];    // s(e mod L), doubled to kill the mod
    __shared__ float psum[8][32];
    __shared__ float salt[32];

    // stage xl transposed (coalesced float4 global reads)
    {
        const float* src = xl + (size_t)b * L * D_SZ + c0;
        const int f = tid & 7;           // float4 slot within the 32-ch row
        for (int n = tid >> 3; n < L; n += 32) {
            float4 v = *(const float4*)(src + (size_t)n * D_SZ + 4 * f);
            xst[4 * f + 0][n] = v.x;
            xst[4 * f + 1][n] = v.y;
            xst[4 * f + 2][n] = v.z;
            xst[4 * f + 3][n] = v.w;
        }
    }
    for (int idx = tid; idx < 2 * L; idx += 256) {
        int e = (idx >= L) ? idx - L : idx;
        double th = M_PI * (2.0 * e + 1.0) / (2.0 * L);
        double ct = cos(th) / sin(th);
        stab_ext[idx] = (float)((e & 1) ? -ct : ct);
    }
    __syncthreads();

    // alternating sum, parallel over 8 r-groups
    {
        float s = 0.f;
        const int n0 = r * (L / 8);
        for (int k = 0; k < L / 8; ++k) {
            float v = xst[c][n0 + k];
            s += ((n0 + k) & 1) ? -v : v;
        }
        psum[r][c] = s;
    }
    __syncthreads();
    if (tid < 32) {
        float s = 0.f;
        for (int rr = 0; rr < 8; ++rr) s += psum[rr][tid];
        salt[tid] = s;
    }
    __syncthreads();

    const float inv4L = 1.0f / (4.0f * (float)L);
    const int P = (L + 127) / 128;                  // passes of 128 t-rows
    const size_t outbase = (size_t)b * (2 * L) * D_SZ + c0 + c;

    for (int p = 0; p < P; ++p) {
        const int T0 = p * 128 + r * 16;
        if (T0 >= L) continue;                      // L=64: r>=4 idle here

        float acc[16];
        #pragma unroll
        for (int j = 0; j < 16; ++j) acc[j] = 0.f;

        // s-window: sw[m] = stab_ext[L+T0-n0-8+m], m in [0,24); used m=1..23
        float sw[24];
        int sbase = L + T0 - 8;
        #pragma unroll
        for (int m = 0; m < 24; m += 4) {
            float4 v = *(const float4*)&stab_ext[sbase + m];
            sw[m] = v.x; sw[m + 1] = v.y; sw[m + 2] = v.z; sw[m + 3] = v.w;
        }

        for (int n0 = 0; n0 < L; n0 += 8) {
            float xa[8];
            #pragma unroll
            for (int m = 0; m < 8; m += 4) {
                float4 v = *(const float4*)&xst[c][n0 + m];
                xa[m] = v.x; xa[m + 1] = v.y; xa[m + 2] = v.z; xa[m + 3] = v.w;
            }
            #pragma unroll
            for (int d = 0; d < 8; ++d) {
                #pragma unroll
                for (int j = 0; j < 16; ++j) {
                    // s((t-n) mod L) with t=T0+j, n=n0+d  ->  sw[8+j-d]
                    acc[j] = fmaf(xa[d], sw[8 + j - d], acc[j]);
                }
            }
            if (n0 + 8 < L) {   // slide window down by 8
                #pragma unroll
                for (int m = 23; m >= 8; --m) sw[m] = sw[m - 8];
                sbase -= 8;
                #pragma unroll
                for (int m = 0; m < 8; m += 4) {
                    float4 v = *(const float4*)&stab_ext[sbase + m];
                    sw[m] = v.x; sw[m + 1] = v.y; sw[m + 2] = v.z; sw[m + 3] = v.w;
                }
            }
        }

        const float sc = salt[c] * inv4L;
        #pragma unroll
        for (int j = 0; j < 16; ++j) {
            int t = T0 + j;
            size_t io = outbase + (size_t)(2 * t + 1) * D_SZ;
            out[io] = xh[io] + sign * (acc[j] * inv4L);
            size_t ie = outbase + (size_t)(2 * t) * D_SZ;
            float up = 0.25f * xst[c][t] + ((t & 1) ? -sc : sc);
            out[ie] = xh[ie] + sign * up;
        }
    }
}

// ---------------------------------------------------------------------------
// mkan_kernel<L,DEG1,NT>: out[b,n,o] = sum_{i,d} T_d(tanh(tanh(x[b,n,i]))) *
//   coeffs[i,o,d]  +  depthwise conv3 (zero-padded) of x with w[o,0..2].
// (unchanged from R0 — MFMA rewrite is the next experiment)
// ---------------------------------------------------------------------------
template<int L, int DEG1, int NT>
__global__ __launch_bounds__(256) void mkan_kernel(
    const float* __restrict__ x,      // (B, L, 128)
    const float* __restrict__ coeffs, // (128, 128, DEG1)
    const float* __restrict__ w,      // (128, 3)
    float* __restrict__ out)          // (B, L, 128)
{
    const int b   = blockIdx.x;
    const int n0  = blockIdx.y * NT;
    const int tid = threadIdx.x;

    __shared__ float xr[NT + 2][D_SZ];  // raw rows n0-1 .. n0+NT (zero-padded)
    __shared__ float tt[NT][D_SZ];      // tanh(tanh(x)) rows n0 .. n0+NT-1

    for (int idx = tid; idx < (NT + 2) * D_SZ; idx += 256) {
        int rr = idx >> 7, c = idx & 127;
        int n = n0 - 1 + rr;
        float v = 0.f;
        if (n >= 0 && n < L) v = x[((size_t)b * L + n) * D_SZ + c];
        xr[rr][c] = v;
    }
    __syncthreads();
    for (int idx = tid; idx < NT * D_SZ; idx += 256) {
        int nl = idx >> 7, c = idx & 127;
        tt[nl][c] = tanhf(tanhf(xr[nl + 1][c]));
    }
    __syncthreads();

    const int o  = tid & 127;
    const int ng = tid >> 7;            // 0 or 1
    const float w0 = w[o * 3 + 0], w1 = w[o * 3 + 1], w2 = w[o * 3 + 2];

    float acc[NT / 2];
    #pragma unroll
    for (int j = 0; j < NT / 2; ++j) {
        int nl = ng + 2 * j;            // xr row nl == global n-1 for this output
        acc[j] = xr[nl][o] * w0 + xr[nl + 1][o] * w1 + xr[nl + 2][o] * w2;
    }

    for (int i = 0; i < D_SZ; ++i) {
        const float* cb = coeffs + ((size_t)i * D_SZ + o) * DEG1;
        float cd[DEG1];
        #pragma unroll
        for (int d = 0; d < DEG1; ++d) cd[d] = cb[d];
        #pragma unroll
        for (int j = 0; j < NT / 2; ++j) {
            float t  = tt[ng + 2 * j][i];   // wave-uniform -> LDS broadcast
            float s  = fmaf(cd[1], t, cd[0]);
            float tp = 1.f, tc = t, t2 = t + t;
            #pragma unroll
            for (int d = 2; d < DEG1; ++d) {
                float tn = fmaf(t2, tc, -tp);
                s = fmaf(cd[d], tn, s);
                tp = tc; tc = tn;
            }
            acc[j] += s;
        }
    }

    #pragma unroll
    for (int j = 0; j < NT / 2; ++j) {
        int n = n0 + ng + 2 * j;
        out[((size_t)b * L + n) * D_SZ + o] = acc[j];
    }
}

extern "C" void kernel_launch(void* const* d_in, const int* in_sizes, int n_in,
                              void* d_out, int out_size, void* d_ws, size_t ws_size,
                              hipStream_t stream) {
    const float* x0 = (const float*)d_in[0];   // (128, 512, 128)
    const float* x1 = (const float*)d_in[1];   // (128, 256, 128)
    const float* x2 = (const float*)d_in[2];   // (128, 128, 128)
    const float* x3 = (const float*)d_in[3];   // (128,  64, 128)
    const float* c0 = (const float*)d_in[4];   // (128,128,2)
    const float* w0 = (const float*)d_in[5];
    const float* c1 = (const float*)d_in[6];   // (128,128,3)
    const float* w1 = (const float*)d_in[7];
    const float* c2 = (const float*)d_in[8];   // (128,128,4)
    const float* w2 = (const float*)d_in[9];
    const float* c3 = (const float*)d_in[10];  // (128,128,5)
    const float* w3 = (const float*)d_in[11];
    float* out = (float*)d_out;

    // workspace: dec residuals (58.7 MB total)
    float* d0 = (float*)d_ws;                        // (128,512,128)
    float* d1 = d0 + (size_t)B_SZ * 512 * D_SZ;      // (128,256,128)
    float* d2 = d1 + (size_t)B_SZ * 256 * D_SZ;      // (128,128,128)

    // outputs concatenated in return order: (m3, m2, m1, m0)
    float* m3 = out;                                 // (128,512,128)
    float* m2 = m3 + (size_t)B_SZ * 512 * D_SZ;      // (128,256,128)
    float* m1 = m2 + (size_t)B_SZ * 256 * D_SZ;      // (128,128,128)
    float* m0 = m1 + (size_t)B_SZ * 128 * D_SZ;      // (128, 64,128)

    dim3 blk(256);

    // --- decomposition: d_i = x_i - up2(x_{i+1})  (independent) ---
    up2_combine<64 ><<<dim3(B_SZ, 4), blk, 0, stream>>>(x3, x2, d2, -1.f);
    up2_combine<128><<<dim3(B_SZ, 4), blk, 0, stream>>>(x2, x1, d1, -1.f);
    up2_combine<256><<<dim3(B_SZ, 4), blk, 0, stream>>>(x1, x0, d0, -1.f);

    // --- mixing chain ---
    mkan_kernel<64, 2, 32><<<dim3(B_SZ, 64 / 32), blk, 0, stream>>>(x3, c0, w0, m0);

    mkan_kernel<128, 3, 32><<<dim3(B_SZ, 128 / 32), blk, 0, stream>>>(d2, c1, w1, m1);
    up2_combine<64 ><<<dim3(B_SZ, 4), blk, 0, stream>>>(m0, m1, m1, 1.f);

    mkan_kernel<256, 4, 32><<<dim3(B_SZ, 256 / 32), blk, 0, stream>>>(d1, c2, w2, m2);
    up2_combine<128><<<dim3(B_SZ, 4), blk, 0, stream>>>(m1, m2, m2, 1.f);

    mkan_kernel<512, 5, 32><<<dim3(B_SZ, 512 / 32), blk, 0, stream>>>(d0, c3, w3, m3);
    up2_combine<256><<<dim3(B_SZ, 4), blk, 0, stream>>>(m2, m3, m3, 1.f);
}

// Round 3
// 376.777 us; speedup vs baseline: 2.5630x; 1.6550x over previous
//
#include <hip/hip_runtime.h>
#include <math.h>

#define B_SZ 128
#define D_SZ 128

typedef __attribute__((ext_vector_type(8))) short bf16x8;
typedef __attribute__((ext_vector_type(4))) float f32x4;

__device__ __forceinline__ unsigned short f2bf(float f) {
    unsigned u = __float_as_uint(f);
    unsigned r = (u + 0x7FFF + ((u >> 16) & 1)) >> 16;   // RNE; inputs finite
    return (unsigned short)r;
}

// ---------------------------------------------------------------------------
// up2_combine<L>  (UNCHANGED from R1 — awaiting counter evidence; after the
// mkan shrink its dispatches will surface in top-5 with VGPR/LDS counters)
// ---------------------------------------------------------------------------
template<int L>
__global__ __launch_bounds__(256) void up2_combine(
    const float* __restrict__ xl, const float* __restrict__ xh,
    float* __restrict__ out, float sign)
{
    const int b   = blockIdx.x;
    const int c0  = blockIdx.y * 32;
    const int tid = threadIdx.x;
    const int c   = tid & 31;
    const int r   = tid >> 5;

    __shared__ float xst[32][L + 4];
    __shared__ float stab_ext[2 * L];
    __shared__ float psum[8][32];
    __shared__ float salt[32];

    {
        const float* src = xl + (size_t)b * L * D_SZ + c0;
        const int f = tid & 7;
        for (int n = tid >> 3; n < L; n += 32) {
            float4 v = *(const float4*)(src + (size_t)n * D_SZ + 4 * f);
            xst[4 * f + 0][n] = v.x;
            xst[4 * f + 1][n] = v.y;
            xst[4 * f + 2][n] = v.z;
            xst[4 * f + 3][n] = v.w;
        }
    }
    for (int idx = tid; idx < 2 * L; idx += 256) {
        int e = (idx >= L) ? idx - L : idx;
        double th = M_PI * (2.0 * e + 1.0) / (2.0 * L);
        double ct = cos(th) / sin(th);
        stab_ext[idx] = (float)((e & 1) ? -ct : ct);
    }
    __syncthreads();

    {
        float s = 0.f;
        const int n0 = r * (L / 8);
        for (int k = 0; k < L / 8; ++k) {
            float v = xst[c][n0 + k];
            s += ((n0 + k) & 1) ? -v : v;
        }
        psum[r][c] = s;
    }
    __syncthreads();
    if (tid < 32) {
        float s = 0.f;
        for (int rr = 0; rr < 8; ++rr) s += psum[rr][tid];
        salt[tid] = s;
    }
    __syncthreads();

    const float inv4L = 1.0f / (4.0f * (float)L);
    const int P = (L + 127) / 128;
    const size_t outbase = (size_t)b * (2 * L) * D_SZ + c0 + c;

    for (int p = 0; p < P; ++p) {
        const int T0 = p * 128 + r * 16;
        if (T0 >= L) continue;

        float acc[16];
        #pragma unroll
        for (int j = 0; j < 16; ++j) acc[j] = 0.f;

        float sw[24];
        int sbase = L + T0 - 8;
        #pragma unroll
        for (int m = 0; m < 24; m += 4) {
            float4 v = *(const float4*)&stab_ext[sbase + m];
            sw[m] = v.x; sw[m + 1] = v.y; sw[m + 2] = v.z; sw[m + 3] = v.w;
        }

        for (int n0 = 0; n0 < L; n0 += 8) {
            float xa[8];
            #pragma unroll
            for (int m = 0; m < 8; m += 4) {
                float4 v = *(const float4*)&xst[c][n0 + m];
                xa[m] = v.x; xa[m + 1] = v.y; xa[m + 2] = v.z; xa[m + 3] = v.w;
            }
            #pragma unroll
            for (int d = 0; d < 8; ++d) {
                #pragma unroll
                for (int j = 0; j < 16; ++j) {
                    acc[j] = fmaf(xa[d], sw[8 + j - d], acc[j]);
                }
            }
            if (n0 + 8 < L) {
                #pragma unroll
                for (int m = 23; m >= 8; --m) sw[m] = sw[m - 8];
                sbase -= 8;
                #pragma unroll
                for (int m = 0; m < 8; m += 4) {
                    float4 v = *(const float4*)&stab_ext[sbase + m];
                    sw[m] = v.x; sw[m + 1] = v.y; sw[m + 2] = v.z; sw[m + 3] = v.w;
                }
            }
        }

        const float sc = salt[c] * inv4L;
        #pragma unroll
        for (int j = 0; j < 16; ++j) {
            int t = T0 + j;
            size_t io = outbase + (size_t)(2 * t + 1) * D_SZ;
            out[io] = xh[io] + sign * (acc[j] * inv4L);
            size_t ie = outbase + (size_t)(2 * t) * D_SZ;
            float up = 0.25f * xst[c][t] + ((t & 1) ? -sc : sc);
            out[ie] = xh[ie] + sign * up;
        }
    }
}

// ---------------------------------------------------------------------------
// convb<DEG1>: BmT[d-1][o][i] = bf16(coeffs[i,o,d]) for d>=1;
//              bias[o] = sum_i coeffs[i,o,0]   (T_0 == 1 plane folded out)
// grid 128 (o), block 128 (i). Tiny.
// ---------------------------------------------------------------------------
template<int DEG1>
__global__ __launch_bounds__(128) void convb(
    const float* __restrict__ coeffs, unsigned short* __restrict__ BmT,
    float* __restrict__ bias)
{
    const int o = blockIdx.x, i = threadIdx.x;
    const float* cp = coeffs + ((size_t)i * 128 + o) * DEG1;
    float c0 = cp[0];
    #pragma unroll
    for (int d = 1; d < DEG1; ++d)
        BmT[(size_t)(d - 1) * 16384 + o * 128 + i] = f2bf(cp[d]);

    __shared__ float red[2];
    float s = c0;
    #pragma unroll
    for (int off = 32; off >= 1; off >>= 1) s += __shfl_down(s, off);
    if ((i & 63) == 0) red[i >> 6] = s;
    __syncthreads();
    if (i == 0) bias[o] = red[0] + red[1];
}

// ---------------------------------------------------------------------------
// prep_T<DEG1>: u = tanh(tanh(x)); Tw[p][row][i] = bf16(T_{p+1}(u)), p<DEG1-1
// (fp32 recurrence, rounded per plane). Thread = (row, i-pair).
// ---------------------------------------------------------------------------
template<int DEG1>
__global__ __launch_bounds__(256) void prep_T(
    const float* __restrict__ x, unsigned short* __restrict__ Tw,
    int m_base, int Mc)
{
    const int s = blockIdx.x * 256 + threadIdx.x;
    const int row = s >> 6;
    const int i0 = (s & 63) * 2;
    const float2 xv = *(const float2*)(x + ((size_t)(m_base + row)) * 128 + i0);
    float u0 = tanhf(tanhf(xv.x)), u1 = tanhf(tanhf(xv.y));
    float tp0 = 1.f, tp1 = 1.f, tc0 = u0, tc1 = u1;
    const size_t plane = (size_t)Mc * 128;
    size_t off = (size_t)row * 128 + i0;
    #pragma unroll
    for (int p = 0; p < DEG1 - 1; ++p) {
        ushort2 o2 = { f2bf(tc0), f2bf(tc1) };
        *(ushort2*)(Tw + p * plane + off) = o2;
        float tn0 = fmaf(2.f * u0, tc0, -tp0);
        float tn1 = fmaf(2.f * u1, tc1, -tp1);
        tp0 = tc0; tc0 = tn0; tp1 = tc1; tc1 = tn1;
    }
}

// ---------------------------------------------------------------------------
// mkan_gemm<DEG1>: C[m,o] = sum_k Tw[m,k]*Bm[k,o] + bias[o] + dwconv3(x)[m,o]
// Block: 64(M) x 128(N), 4 waves of 32x64 (2x2), mfma_f32_16x16x32_bf16,
// double-buffered LDS tiles (A 64x32, B^T 128x32), K = (DEG1-1)*128.
// A layout [m=ln&15][k=quad*8+j], B read from o-major tile -> B[k][n=ln&15];
// C/D: col=ln&15, row=quad*4+reg (m89/m91-verified mapping).
// ---------------------------------------------------------------------------
template<int DEG1>
__global__ __launch_bounds__(256) void mkan_gemm(
    const unsigned short* __restrict__ Tw,   // (DEG1-1, Mc, 128)
    const unsigned short* __restrict__ BmT,  // (DEG1-1, 128, 128) [d][o][i]
    const float* __restrict__ bias,          // (128)
    const float* __restrict__ x,             // level input, (B*L, 128)
    const float* __restrict__ w,             // (128, 3)
    float* __restrict__ out,                 // (B*L, 128)
    int m_base, int Mc, int L)
{
    constexpr int NK = (DEG1 - 1) * 4;       // K-chunks of 32
    const int tid = threadIdx.x;
    const int mb  = blockIdx.x * 64;         // chunk-local row base

    __shared__ unsigned short Ab[2][64 * 32];
    __shared__ unsigned short Bb[2][128 * 32];

    const int ln = tid & 63;
    const int wv = tid >> 6;
    const int wm = wv & 1;                   // M half (rows wm*32..+31)
    const int wn = wv >> 1;                  // N half (cols wn*64..+63)
    const int lr = ln & 15;                  // row/col within 16-tile
    const int qd = ln >> 4;                  // quad 0..3

    f32x4 acc[2][4];
    #pragma unroll
    for (int mt = 0; mt < 2; ++mt)
        #pragma unroll
        for (int nt = 0; nt < 4; ++nt)
            acc[mt][nt] = (f32x4){0.f, 0.f, 0.f, 0.f};

    // staging: thread t -> A slot t (64x32 tile, offset t*8 ushorts),
    //          B slots t and t+256 (128x32 tile)
    const int arow = tid >> 2, acol = (tid & 3) * 8;

    auto stage = [&](int kk, int buf) {
        const int p = kk >> 2, i0 = (kk & 3) * 32;
        const unsigned short* ga =
            Tw + ((size_t)p * Mc + mb + arow) * 128 + i0 + acol;
        ((bf16x8*)Ab[buf])[tid] = *(const bf16x8*)ga;
        #pragma unroll
        for (int j = 0; j < 2; ++j) {
            int sidx = tid + 256 * j;
            const unsigned short* gb =
                BmT + ((size_t)p * 128 + (sidx >> 2)) * 128 + i0 + (sidx & 3) * 8;
            ((bf16x8*)Bb[buf])[sidx] = *(const bf16x8*)gb;
        }
    };

    stage(0, 0);
    for (int kk = 0; kk < NK; ++kk) {
        __syncthreads();
        if (kk + 1 < NK) stage(kk + 1, (kk + 1) & 1);
        const int buf = kk & 1;
        bf16x8 af[2], bfv[4];
        #pragma unroll
        for (int mt = 0; mt < 2; ++mt)
            af[mt] = *(const bf16x8*)&Ab[buf][(wm * 32 + mt * 16 + lr) * 32 + qd * 8];
        #pragma unroll
        for (int nt = 0; nt < 4; ++nt)
            bfv[nt] = *(const bf16x8*)&Bb[buf][(wn * 64 + nt * 16 + lr) * 32 + qd * 8];
        #pragma unroll
        for (int mt = 0; mt < 2; ++mt)
            #pragma unroll
            for (int nt = 0; nt < 4; ++nt)
                acc[mt][nt] = __builtin_amdgcn_mfma_f32_16x16x32_bf16(
                    af[mt], bfv[nt], acc[mt][nt], 0, 0, 0);
    }

    // epilogue: bias + depthwise conv3 (zero-padded within each b's L rows)
    const int gm0 = m_base + mb;
    #pragma unroll
    for (int nt = 0; nt < 4; ++nt) {
        const int col = wn * 64 + nt * 16 + lr;
        const float w0 = w[col * 3 + 0], w1 = w[col * 3 + 1], w2 = w[col * 3 + 2];
        const float bs = bias[col];
        #pragma unroll
        for (int mt = 0; mt < 2; ++mt) {
            #pragma unroll
            for (int r = 0; r < 4; ++r) {
                const int row = wm * 32 + mt * 16 + qd * 4 + r;
                const int gm = gm0 + row;
                const int n = gm & (L - 1);
                const size_t gi = (size_t)gm * 128 + col;
                float xm1 = (n > 0)     ? x[gi - 128] : 0.f;
                float x0v = x[gi];
                float xp1 = (n < L - 1) ? x[gi + 128] : 0.f;
                out[gi] = acc[mt][nt][r] + bs +
                          fmaf(w0, xm1, fmaf(w1, x0v, w2 * xp1));
            }
        }
    }
}

// ---------------------------------------------------------------------------
extern "C" void kernel_launch(void* const* d_in, const int* in_sizes, int n_in,
                              void* d_out, int out_size, void* d_ws, size_t ws_size,
                              hipStream_t stream) {
    const float* x0 = (const float*)d_in[0];
    const float* x1 = (const float*)d_in[1];
    const float* x2 = (const float*)d_in[2];
    const float* x3 = (const float*)d_in[3];
    const float* c0 = (const float*)d_in[4];
    const float* w0 = (const float*)d_in[5];
    const float* c1 = (const float*)d_in[6];
    const float* w1 = (const float*)d_in[7];
    const float* c2 = (const float*)d_in[8];
    const float* w2 = (const float*)d_in[9];
    const float* c3 = (const float*)d_in[10];
    const float* w3 = (const float*)d_in[11];
    float* out = (float*)d_out;

    // ws layout: dec residuals + Tw chunk (32768 rows x 4 planes) + BmT + bias
    float* d0 = (float*)d_ws;                               // 8388608 f
    float* d1 = d0 + (size_t)B_SZ * 512 * D_SZ;             // 4194304 f
    float* d2 = d1 + (size_t)B_SZ * 256 * D_SZ;             // 2097152 f
    unsigned short* Tw  = (unsigned short*)(d2 + (size_t)B_SZ * 128 * D_SZ);
    unsigned short* BmT = Tw + (size_t)4 * 32768 * 128;     // 16.78M ushorts
    float* bias = (float*)(BmT + 4 * 128 * 128);

    float* m3 = out;
    float* m2 = m3 + (size_t)B_SZ * 512 * D_SZ;
    float* m1 = m2 + (size_t)B_SZ * 256 * D_SZ;
    float* m0 = m1 + (size_t)B_SZ * 128 * D_SZ;

    dim3 blk(256);
    const int CHUNK = 32768;

    auto run_mkan = [&](auto deg_tag, const float* xin, const float* cc,
                        const float* ww, float* outp, int L) {
        constexpr int DEG1 = decltype(deg_tag)::value;
        convb<DEG1><<<128, 128, 0, stream>>>(cc, BmT, bias);
        const int M = B_SZ * L;
        for (int m0b = 0; m0b < M; m0b += CHUNK) {
            const int Mc = (M - m0b < CHUNK) ? (M - m0b) : CHUNK;
            prep_T<DEG1><<<Mc / 4, 256, 0, stream>>>(xin, Tw, m0b, Mc);
            mkan_gemm<DEG1><<<Mc / 64, 256, 0, stream>>>(
                Tw, BmT, bias, xin, ww, outp, m0b, Mc, L);
        }
    };

    // --- decomposition: d_i = x_i - up2(x_{i+1}) ---
    up2_combine<64 ><<<dim3(B_SZ, 4), blk, 0, stream>>>(x3, x2, d2, -1.f);
    up2_combine<128><<<dim3(B_SZ, 4), blk, 0, stream>>>(x2, x1, d1, -1.f);
    up2_combine<256><<<dim3(B_SZ, 4), blk, 0, stream>>>(x1, x0, d0, -1.f);

    // --- mixing chain ---
    run_mkan(std::integral_constant<int, 2>{}, x3, c0, w0, m0, 64);

    run_mkan(std::integral_constant<int, 3>{}, d2, c1, w1, m1, 128);
    up2_combine<64 ><<<dim3(B_SZ, 4), blk, 0, stream>>>(m0, m1, m1, 1.f);

    run_mkan(std::integral_constant<int, 4>{}, d1, c2, w2, m2, 256);
    up2_combine<128><<<dim3(B_SZ, 4), blk, 0, stream>>>(m1, m2, m2, 1.f);

    run_mkan(std::integral_constant<int, 5>{}, d0, c3, w3, m3, 512);
    up2_combine<256><<<dim3(B_SZ, 4), blk, 0, stream>>>(m2, m3, m3, 1.f);
}

// Round 4
// 368.435 us; speedup vs baseline: 2.6210x; 1.0226x over previous
//
#include <hip/hip_runtime.h>
#include <math.h>
#include <type_traits>

#define B_SZ 128
#define D_SZ 128

typedef __attribute__((ext_vector_type(8))) short bf16x8;
typedef __attribute__((ext_vector_type(4))) float f32x4;

__device__ __forceinline__ unsigned short f2bf(float f) {
    unsigned u = __float_as_uint(f);
    unsigned r = (u + 0x7FFF + ((u >> 16) & 1)) >> 16;   // RNE; inputs finite
    return (unsigned short)r;
}

// ---------------------------------------------------------------------------
// build_U: materialize the three 2L x L up-sample matrices (bf16, 1/4L folded).
//   U[2t,n]   = (t==n)*0.25 + (-1)^{t+n}/(4L)    (exact in bf16 for the
//               parity term; diagonal 0.25+2^-10 half-ulp-rounds at L=256)
//   U[2t+1,n] = (-1)^e * cot(pi*(2e+1)/(2L))/(4L),  e=(t-n) mod L
// One flat grid covers U256|U128|U64 (131072+32768+8192 = 172032 elements).
// ---------------------------------------------------------------------------
__global__ __launch_bounds__(256) void build_U(
    unsigned short* __restrict__ U256,
    unsigned short* __restrict__ U128,
    unsigned short* __restrict__ U64)
{
    int fid = blockIdx.x * 256 + threadIdx.x;
    unsigned short* U; int L, lg, e;
    if (fid < 131072)      { U = U256; L = 256; lg = 8; e = fid; }
    else if (fid < 163840) { U = U128; L = 128; lg = 7; e = fid - 131072; }
    else                   { U = U64;  L = 64;  lg = 6; e = fid - 163840; }
    const int n = e & (L - 1);
    const int m = e >> lg;
    const int t = m >> 1;
    const float inv4L = 1.0f / (4.0f * (float)L);
    float val;
    if ((m & 1) == 0) {
        val = ((t == n) ? 0.25f : 0.0f) + (((t + n) & 1) ? -inv4L : inv4L);
    } else {
        int idx = (t - n) & (L - 1);
        double th = M_PI * (2.0 * idx + 1.0) / (2.0 * L);
        double ct = cos(th) / sin(th);
        val = (float)((idx & 1) ? -ct : ct) * inv4L;
    }
    U[e] = f2bf(val);
}

// ---------------------------------------------------------------------------
// castT_tile: one 64(n) x 128(c) tile of fp32 (B,L,128) -> bf16 (B,128,L).
// Coalesced float4 reads; LDS transpose (row stride 72 ushorts); 16B writes.
// ---------------------------------------------------------------------------
__device__ __forceinline__ void castT_tile(
    const float* __restrict__ src, unsigned short* __restrict__ dst,
    int b, int n0, int L)
{
    __shared__ unsigned short tt[128][72];
    const int tid = threadIdx.x;
    for (int i = tid; i < 64 * 32; i += 256) {
        int nr = i >> 5, c4 = (i & 31) * 4;
        float4 v = *(const float4*)(src + ((size_t)b * L + n0 + nr) * 128 + c4);
        tt[c4 + 0][nr] = f2bf(v.x);
        tt[c4 + 1][nr] = f2bf(v.y);
        tt[c4 + 2][nr] = f2bf(v.z);
        tt[c4 + 3][nr] = f2bf(v.w);
    }
    __syncthreads();
    const int c = tid >> 1, seg = (tid & 1) * 32;
    unsigned short* dp = dst + ((size_t)b * 128 + c) * L + n0 + seg;
    #pragma unroll
    for (int j = 0; j < 32; j += 8)
        *(bf16x8*)(dp + j) = *(const bf16x8*)&tt[c][seg + j];
}

// dec casts fused: x1 (L=256, 512 blocks) | x2 (L=128, 256) | x3 (L=64, 128)
__global__ __launch_bounds__(256) void castT_dec(
    const float* __restrict__ x1, const float* __restrict__ x2,
    const float* __restrict__ x3,
    unsigned short* __restrict__ Xt1, unsigned short* __restrict__ Xt2,
    unsigned short* __restrict__ Xt3)
{
    const int bid = blockIdx.x;
    if (bid < 512)      castT_tile(x1, Xt1, bid >> 2, (bid & 3) * 64, 256);
    else if (bid < 768) castT_tile(x2, Xt2, (bid - 512) >> 1, ((bid - 512) & 1) * 64, 128);
    else                castT_tile(x3, Xt3, bid - 768, 0, 64);
}

template<int L>
__global__ __launch_bounds__(256) void castT_mix(
    const float* __restrict__ src, unsigned short* __restrict__ dst)
{
    constexpr int NT = L / 64;
    const int b = blockIdx.x / NT, t = blockIdx.x % NT;
    castT_tile(src, dst, b, t * 64, L);
}

// ---------------------------------------------------------------------------
// up2_gemm<L>: out[b,m,c] = xh[b,m,c] + sign * sum_n U[m,n]*Xt[b,c,n]
// M=2L, N=128(c), K=L(n). 64x128 block, 4 waves 2x2 of 32x64,
// mfma_f32_16x16x32_bf16, double-buffered LDS (same verified skeleton as
// mkan_gemm). U is batch-shared (<=256 KB, L3-resident). In-place when
// xh==out (mix chain) — block only touches its own tile.
// ---------------------------------------------------------------------------
template<int L>
__global__ __launch_bounds__(256) void up2_gemm(
    const unsigned short* __restrict__ U,    // (2L, L) bf16
    const unsigned short* __restrict__ Xt,   // (B, 128, L) bf16
    const float* __restrict__ xh,            // (B, 2L, 128)
    float* __restrict__ out,                 // (B, 2L, 128)
    float sign)
{
    constexpr int MT = (2 * L) / 64;         // M-tiles per batch
    constexpr int NK = L / 32;               // K-chunks
    const int b  = blockIdx.x / MT;
    const int mt = blockIdx.x % MT;
    const int tid = threadIdx.x;

    __shared__ unsigned short Ab[2][64 * 32];
    __shared__ unsigned short Bb[2][128 * 32];

    const int ln = tid & 63;
    const int wv = tid >> 6;
    const int wm = wv & 1;
    const int wn = wv >> 1;
    const int lr = ln & 15;
    const int qd = ln >> 4;

    f32x4 acc[2][4];
    #pragma unroll
    for (int mi = 0; mi < 2; ++mi)
        #pragma unroll
        for (int nt = 0; nt < 4; ++nt)
            acc[mi][nt] = (f32x4){0.f, 0.f, 0.f, 0.f};

    const int arow = tid >> 2, acol = (tid & 3) * 8;

    auto stage = [&](int kk, int buf) {
        const unsigned short* ga = U + ((size_t)(mt * 64 + arow)) * L + kk * 32 + acol;
        ((bf16x8*)Ab[buf])[tid] = *(const bf16x8*)ga;
        #pragma unroll
        for (int j = 0; j < 2; ++j) {
            int sidx = tid + 256 * j;
            const unsigned short* gb =
                Xt + ((size_t)b * 128 + (sidx >> 2)) * L + kk * 32 + (sidx & 3) * 8;
            ((bf16x8*)Bb[buf])[sidx] = *(const bf16x8*)gb;
        }
    };

    stage(0, 0);
    for (int kk = 0; kk < NK; ++kk) {
        __syncthreads();
        if (kk + 1 < NK) stage(kk + 1, (kk + 1) & 1);
        const int buf = kk & 1;
        bf16x8 af[2], bfv[4];
        #pragma unroll
        for (int mi = 0; mi < 2; ++mi)
            af[mi] = *(const bf16x8*)&Ab[buf][(wm * 32 + mi * 16 + lr) * 32 + qd * 8];
        #pragma unroll
        for (int nt = 0; nt < 4; ++nt)
            bfv[nt] = *(const bf16x8*)&Bb[buf][(wn * 64 + nt * 16 + lr) * 32 + qd * 8];
        #pragma unroll
        for (int mi = 0; mi < 2; ++mi)
            #pragma unroll
            for (int nt = 0; nt < 4; ++nt)
                acc[mi][nt] = __builtin_amdgcn_mfma_f32_16x16x32_bf16(
                    af[mi], bfv[nt], acc[mi][nt], 0, 0, 0);
    }

    #pragma unroll
    for (int nt = 0; nt < 4; ++nt) {
        const int col = wn * 64 + nt * 16 + lr;
        #pragma unroll
        for (int mi = 0; mi < 2; ++mi) {
            #pragma unroll
            for (int r = 0; r < 4; ++r) {
                const int row = mt * 64 + wm * 32 + mi * 16 + qd * 4 + r;
                const size_t gi = ((size_t)b * (2 * L) + row) * 128 + col;
                out[gi] = xh[gi] + sign * acc[mi][nt][r];
            }
        }
    }
}

// ---------------------------------------------------------------------------
// convb<DEG1>: BmT[d-1][o][i] = bf16(coeffs[i,o,d]); bias[o] = sum_i c[i,o,0]
// ---------------------------------------------------------------------------
template<int DEG1>
__global__ __launch_bounds__(128) void convb(
    const float* __restrict__ coeffs, unsigned short* __restrict__ BmT,
    float* __restrict__ bias)
{
    const int o = blockIdx.x, i = threadIdx.x;
    const float* cp = coeffs + ((size_t)i * 128 + o) * DEG1;
    float c0 = cp[0];
    #pragma unroll
    for (int d = 1; d < DEG1; ++d)
        BmT[(size_t)(d - 1) * 16384 + o * 128 + i] = f2bf(cp[d]);

    __shared__ float red[2];
    float s = c0;
    #pragma unroll
    for (int off = 32; off >= 1; off >>= 1) s += __shfl_down(s, off);
    if ((i & 63) == 0) red[i >> 6] = s;
    __syncthreads();
    if (i == 0) bias[o] = red[0] + red[1];
}

// ---------------------------------------------------------------------------
// prep_T<DEG1>: u = tanh(tanh(x)); Tw[p][row][i] = bf16(T_{p+1}(u))
// ---------------------------------------------------------------------------
template<int DEG1>
__global__ __launch_bounds__(256) void prep_T(
    const float* __restrict__ x, unsigned short* __restrict__ Tw,
    int m_base, int Mc)
{
    const int s = blockIdx.x * 256 + threadIdx.x;
    const int row = s >> 6;
    const int i0 = (s & 63) * 2;
    const float2 xv = *(const float2*)(x + ((size_t)(m_base + row)) * 128 + i0);
    float u0 = tanhf(tanhf(xv.x)), u1 = tanhf(tanhf(xv.y));
    float tp0 = 1.f, tp1 = 1.f, tc0 = u0, tc1 = u1;
    const size_t plane = (size_t)Mc * 128;
    size_t off = (size_t)row * 128 + i0;
    #pragma unroll
    for (int p = 0; p < DEG1 - 1; ++p) {
        ushort2 o2 = { f2bf(tc0), f2bf(tc1) };
        *(ushort2*)(Tw + p * plane + off) = o2;
        float tn0 = fmaf(2.f * u0, tc0, -tp0);
        float tn1 = fmaf(2.f * u1, tc1, -tp1);
        tp0 = tc0; tc0 = tn0; tp1 = tc1; tc1 = tn1;
    }
}

// ---------------------------------------------------------------------------
// mkan_gemm<DEG1> (unchanged, verified R2): cheby GEMM + bias + dwconv3.
// ---------------------------------------------------------------------------
template<int DEG1>
__global__ __launch_bounds__(256) void mkan_gemm(
    const unsigned short* __restrict__ Tw,
    const unsigned short* __restrict__ BmT,
    const float* __restrict__ bias,
    const float* __restrict__ x,
    const float* __restrict__ w,
    float* __restrict__ out,
    int m_base, int Mc, int L)
{
    constexpr int NK = (DEG1 - 1) * 4;
    const int tid = threadIdx.x;
    const int mb  = blockIdx.x * 64;

    __shared__ unsigned short Ab[2][64 * 32];
    __shared__ unsigned short Bb[2][128 * 32];

    const int ln = tid & 63;
    const int wv = tid >> 6;
    const int wm = wv & 1;
    const int wn = wv >> 1;
    const int lr = ln & 15;
    const int qd = ln >> 4;

    f32x4 acc[2][4];
    #pragma unroll
    for (int mi = 0; mi < 2; ++mi)
        #pragma unroll
        for (int nt = 0; nt < 4; ++nt)
            acc[mi][nt] = (f32x4){0.f, 0.f, 0.f, 0.f};

    const int arow = tid >> 2, acol = (tid & 3) * 8;

    auto stage = [&](int kk, int buf) {
        const int p = kk >> 2, i0 = (kk & 3) * 32;
        const unsigned short* ga =
            Tw + ((size_t)p * Mc + mb + arow) * 128 + i0 + acol;
        ((bf16x8*)Ab[buf])[tid] = *(const bf16x8*)ga;
        #pragma unroll
        for (int j = 0; j < 2; ++j) {
            int sidx = tid + 256 * j;
            const unsigned short* gb =
                BmT + ((size_t)p * 128 + (sidx >> 2)) * 128 + i0 + (sidx & 3) * 8;
            ((bf16x8*)Bb[buf])[sidx] = *(const bf16x8*)gb;
        }
    };

    stage(0, 0);
    for (int kk = 0; kk < NK; ++kk) {
        __syncthreads();
        if (kk + 1 < NK) stage(kk + 1, (kk + 1) & 1);
        const int buf = kk & 1;
        bf16x8 af[2], bfv[4];
        #pragma unroll
        for (int mi = 0; mi < 2; ++mi)
            af[mi] = *(const bf16x8*)&Ab[buf][(wm * 32 + mi * 16 + lr) * 32 + qd * 8];
        #pragma unroll
        for (int nt = 0; nt < 4; ++nt)
            bfv[nt] = *(const bf16x8*)&Bb[buf][(wn * 64 + nt * 16 + lr) * 32 + qd * 8];
        #pragma unroll
        for (int mi = 0; mi < 2; ++mi)
            #pragma unroll
            for (int nt = 0; nt < 4; ++nt)
                acc[mi][nt] = __builtin_amdgcn_mfma_f32_16x16x32_bf16(
                    af[mi], bfv[nt], acc[mi][nt], 0, 0, 0);
    }

    const int gm0 = m_base + mb;
    #pragma unroll
    for (int nt = 0; nt < 4; ++nt) {
        const int col = wn * 64 + nt * 16 + lr;
        const float w0 = w[col * 3 + 0], w1 = w[col * 3 + 1], w2 = w[col * 3 + 2];
        const float bs = bias[col];
        #pragma unroll
        for (int mi = 0; mi < 2; ++mi) {
            #pragma unroll
            for (int r = 0; r < 4; ++r) {
                const int row = wm * 32 + mi * 16 + qd * 4 + r;
                const int gm = gm0 + row;
                const int n = gm & (L - 1);
                const size_t gi = (size_t)gm * 128 + col;
                float xm1 = (n > 0)     ? x[gi - 128] : 0.f;
                float x0v = x[gi];
                float xp1 = (n < L - 1) ? x[gi + 128] : 0.f;
                out[gi] = acc[mi][nt][r] + bs +
                          fmaf(w0, xm1, fmaf(w1, x0v, w2 * xp1));
            }
        }
    }
}

// ---------------------------------------------------------------------------
extern "C" void kernel_launch(void* const* d_in, const int* in_sizes, int n_in,
                              void* d_out, int out_size, void* d_ws, size_t ws_size,
                              hipStream_t stream) {
    const float* x0 = (const float*)d_in[0];
    const float* x1 = (const float*)d_in[1];
    const float* x2 = (const float*)d_in[2];
    const float* x3 = (const float*)d_in[3];
    const float* c0 = (const float*)d_in[4];
    const float* w0 = (const float*)d_in[5];
    const float* c1 = (const float*)d_in[6];
    const float* w1 = (const float*)d_in[7];
    const float* c2 = (const float*)d_in[8];
    const float* w2 = (const float*)d_in[9];
    const float* c3 = (const float*)d_in[10];
    const float* w3 = (const float*)d_in[11];
    float* out = (float*)d_out;

    // ws layout (floats): d0 | d1 | d2 | SR(shared 33.5MB) | BmT | bias | U*
    // SR holds Xt1|Xt2|Xt3 (dec casts), then Tw planes, then Xtm (mix casts)
    // — lifetimes strictly interleave on the stream, so they alias safely.
    float* d0 = (float*)d_ws;                           // 8388608 f
    float* d1 = d0 + (size_t)B_SZ * 512 * D_SZ;         // 4194304 f
    float* d2 = d1 + (size_t)B_SZ * 256 * D_SZ;         // 2097152 f
    unsigned short* SR  = (unsigned short*)(d2 + (size_t)B_SZ * 128 * D_SZ);
    unsigned short* Tw  = SR;                           // 16777216 ushorts max
    unsigned short* Xt1 = SR;                           // 4194304
    unsigned short* Xt2 = SR + 4194304;                 // 2097152
    unsigned short* Xt3 = SR + 6291456;                 // 1048576
    unsigned short* Xtm = SR;                           // <= 4194304
    unsigned short* BmT = SR + 16777216;                // 65536
    float* bias = (float*)(BmT + 65536);                // 128 f
    unsigned short* U256 = (unsigned short*)(bias + 128); // 131072
    unsigned short* U128 = U256 + 131072;               // 32768
    unsigned short* U64  = U128 + 32768;                // 8192

    float* m3 = out;
    float* m2 = m3 + (size_t)B_SZ * 512 * D_SZ;
    float* m1 = m2 + (size_t)B_SZ * 256 * D_SZ;
    float* m0 = m1 + (size_t)B_SZ * 128 * D_SZ;

    const int CHUNK = 32768;

    auto run_mkan = [&](auto deg_tag, const float* xin, const float* cc,
                        const float* ww, float* outp, int L) {
        constexpr int DEG1 = decltype(deg_tag)::value;
        convb<DEG1><<<128, 128, 0, stream>>>(cc, BmT, bias);
        const int M = B_SZ * L;
        for (int m0b = 0; m0b < M; m0b += CHUNK) {
            const int Mc = (M - m0b < CHUNK) ? (M - m0b) : CHUNK;
            prep_T<DEG1><<<Mc / 4, 256, 0, stream>>>(xin, Tw, m0b, Mc);
            mkan_gemm<DEG1><<<Mc / 64, 256, 0, stream>>>(
                Tw, BmT, bias, xin, ww, outp, m0b, Mc, L);
        }
    };

    // --- static prep: U matrices + transposed bf16 casts of dec inputs ---
    build_U<<<672, 256, 0, stream>>>(U256, U128, U64);
    castT_dec<<<896, 256, 0, stream>>>(x1, x2, x3, Xt1, Xt2, Xt3);

    // --- decomposition: d_i = x_i - up2(x_{i+1}) ---
    up2_gemm<64 ><<<B_SZ * 2, 256, 0, stream>>>(U64,  Xt3, x2, d2, -1.f);
    up2_gemm<128><<<B_SZ * 4, 256, 0, stream>>>(U128, Xt2, x1, d1, -1.f);
    up2_gemm<256><<<B_SZ * 8, 256, 0, stream>>>(U256, Xt1, x0, d0, -1.f);

    // --- mixing chain ---
    run_mkan(std::integral_constant<int, 2>{}, x3, c0, w0, m0, 64);

    run_mkan(std::integral_constant<int, 3>{}, d2, c1, w1, m1, 128);
    castT_mix<64 ><<<B_SZ * 1, 256, 0, stream>>>(m0, Xtm);
    up2_gemm<64 ><<<B_SZ * 2, 256, 0, stream>>>(U64, Xtm, m1, m1, 1.f);

    run_mkan(std::integral_constant<int, 4>{}, d1, c2, w2, m2, 256);
    castT_mix<128><<<B_SZ * 2, 256, 0, stream>>>(m1, Xtm);
    up2_gemm<128><<<B_SZ * 4, 256, 0, stream>>>(U128, Xtm, m2, m2, 1.f);

    run_mkan(std::integral_constant<int, 5>{}, d0, c3, w3, m3, 512);
    castT_mix<256><<<B_SZ * 4, 256, 0, stream>>>(m2, Xtm);
    up2_gemm<256><<<B_SZ * 8, 256, 0, stream>>>(U256, Xtm, m3, m3, 1.f);
}

// Round 5
// 289.328 us; speedup vs baseline: 3.3376x; 1.2734x over previous
//
#include <hip/hip_runtime.h>
#include <math.h>

#define B_SZ 128
#define D_SZ 128

typedef __attribute__((ext_vector_type(8))) short bf16x8;
typedef __attribute__((ext_vector_type(4))) float f32x4;

__device__ __forceinline__ unsigned short f2bf(float f) {
    unsigned u = __float_as_uint(f);
    unsigned r = (u + 0x7FFF + ((u >> 16) & 1)) >> 16;   // RNE; inputs finite
    return (unsigned short)r;
}

// ---------------------------------------------------------------------------
// castT_tile: one 64(n) x 128(c) tile of fp32 (B,L,128) -> bf16 (B,128,L).
// ---------------------------------------------------------------------------
__device__ __forceinline__ void castT_tile(
    const float* __restrict__ src, unsigned short* __restrict__ dst,
    int b, int n0, int L)
{
    __shared__ unsigned short tt[128][72];
    const int tid = threadIdx.x;
    for (int i = tid; i < 64 * 32; i += 256) {
        int nr = i >> 5, c4 = (i & 31) * 4;
        float4 v = *(const float4*)(src + ((size_t)b * L + n0 + nr) * 128 + c4);
        tt[c4 + 0][nr] = f2bf(v.x);
        tt[c4 + 1][nr] = f2bf(v.y);
        tt[c4 + 2][nr] = f2bf(v.z);
        tt[c4 + 3][nr] = f2bf(v.w);
    }
    __syncthreads();
    const int c = tid >> 1, seg = (tid & 1) * 32;
    unsigned short* dp = dst + ((size_t)b * 128 + c) * L + n0 + seg;
    #pragma unroll
    for (int j = 0; j < 32; j += 8)
        *(bf16x8*)(dp + j) = *(const bf16x8*)&tt[c][seg + j];
}

// ---------------------------------------------------------------------------
// prep_all: ONE dispatch for all independent prep work (R4: was 6 dispatches).
//  blocks [0,896):    castT of x1|x2|x3 -> Xt1|Xt2|Xt3 (bf16 transposed)
//  blocks [896,1568): build U256|U128|U64 upsample matrices (bf16)
//  blocks [1568,1824): convb for all 4 coeff sets -> BmT_all + bias_all
// ---------------------------------------------------------------------------
__global__ __launch_bounds__(256) void prep_all(
    const float* __restrict__ x1, const float* __restrict__ x2,
    const float* __restrict__ x3,
    unsigned short* __restrict__ Xt1, unsigned short* __restrict__ Xt2,
    unsigned short* __restrict__ Xt3,
    unsigned short* __restrict__ U256, unsigned short* __restrict__ U128,
    unsigned short* __restrict__ U64p,
    const float* __restrict__ c0, const float* __restrict__ c1,
    const float* __restrict__ c2, const float* __restrict__ c3,
    unsigned short* __restrict__ BmT_all, float* __restrict__ bias_all)
{
    const int bid = blockIdx.x, tid = threadIdx.x;
    if (bid < 896) {
        if (bid < 512)      castT_tile(x1, Xt1, bid >> 2, (bid & 3) * 64, 256);
        else if (bid < 768) castT_tile(x2, Xt2, (bid - 512) >> 1, ((bid - 512) & 1) * 64, 128);
        else                castT_tile(x3, Xt3, bid - 768, 0, 64);
    } else if (bid < 1568) {
        // U[2t,n] = (t==n)*0.25 + (-1)^{t+n}/4L ; U[2t+1,n] = s((t-n)%L)/4L
        int fid = (bid - 896) * 256 + tid;
        unsigned short* U; int L, lg, e;
        if (fid < 131072)      { U = U256; L = 256; lg = 8; e = fid; }
        else if (fid < 163840) { U = U128; L = 128; lg = 7; e = fid - 131072; }
        else                   { U = U64p; L = 64;  lg = 6; e = fid - 163840; }
        const int n = e & (L - 1);
        const int m = e >> lg;
        const int t = m >> 1;
        const float inv4L = 1.0f / (4.0f * (float)L);
        float val;
        if ((m & 1) == 0) {
            val = ((t == n) ? 0.25f : 0.0f) + (((t + n) & 1) ? -inv4L : inv4L);
        } else {
            int idx = (t - n) & (L - 1);
            double th = M_PI * (2.0 * idx + 1.0) / (2.0 * L);
            double ct = cos(th) / sin(th);
            val = (float)((idx & 1) ? -ct : ct) * inv4L;
        }
        U[e] = f2bf(val);
    } else {
        // convb: BmT[set][d-1][o][i] = bf16(coeffs[i,o,d]); bias = sum_i c[i,o,0]
        const int r   = bid - 1568;          // 0..255
        const int set = r >> 6;              // 0..3  (DEG1 = set+2)
        const int o   = ((r & 63) << 1) + (tid >> 7);
        const int i   = tid & 127;
        const int DEG1 = set + 2;
        const float* cc = (set == 0) ? c0 : (set == 1) ? c1 : (set == 2) ? c2 : c3;
        const float* cp = cc + ((size_t)i * 128 + o) * DEG1;
        unsigned short* Bm = BmT_all + (size_t)set * 65536;
        for (int d = 1; d < DEG1; ++d)
            Bm[(size_t)(d - 1) * 16384 + o * 128 + i] = f2bf(cp[d]);
        float s = cp[0];
        #pragma unroll
        for (int off = 32; off >= 1; off >>= 1) s += __shfl_down(s, off);
        __shared__ float red[4];
        if ((tid & 63) == 0) red[tid >> 6] = s;
        __syncthreads();
        if ((tid & 127) == 0)
            bias_all[set * 128 + o] = red[tid >> 6] + red[(tid >> 6) + 1];
    }
}

// ---------------------------------------------------------------------------
// up2_body: out[b,m,c] = xh[b,m,c] + sign * sum_n U[m,n]*Xt[b,c,n]
// 64x128 tile, 4 waves 2x2 of 32x64, mfma 16x16x32 bf16, runtime L
// (same verified skeleton as R3/R4 up2_gemm). Optional bf16-transposed
// copy of the result -> xtm (feeds the next up2 level, kills castT_mix).
// ---------------------------------------------------------------------------
__device__ __forceinline__ void up2_body(
    const unsigned short* __restrict__ U,
    const unsigned short* __restrict__ Xt,
    const float* __restrict__ xh,
    float* __restrict__ out,
    unsigned short* __restrict__ xtm,
    float sign, int b, int mt, int L)
{
    const int NK = L >> 5;
    const int tid = threadIdx.x;
    __shared__ unsigned short Ab[2][2048];
    __shared__ unsigned short Bb[2][4096];

    const int ln = tid & 63, wv = tid >> 6;
    const int wm = wv & 1, wn = wv >> 1;
    const int lr = ln & 15, qd = ln >> 4;

    f32x4 acc[2][4];
    #pragma unroll
    for (int mi = 0; mi < 2; ++mi)
        #pragma unroll
        for (int nt = 0; nt < 4; ++nt)
            acc[mi][nt] = (f32x4){0.f, 0.f, 0.f, 0.f};

    const int arow = tid >> 2, acol = (tid & 3) * 8;

    auto stage = [&](int kk, int buf) {
        const unsigned short* ga = U + (size_t)(mt * 64 + arow) * L + kk * 32 + acol;
        ((bf16x8*)Ab[buf])[tid] = *(const bf16x8*)ga;
        #pragma unroll
        for (int j = 0; j < 2; ++j) {
            int sidx = tid + (j << 8);
            const unsigned short* gb =
                Xt + ((size_t)b * 128 + (sidx >> 2)) * L + kk * 32 + (sidx & 3) * 8;
            ((bf16x8*)Bb[buf])[sidx] = *(const bf16x8*)gb;
        }
    };

    stage(0, 0);
    for (int kk = 0; kk < NK; ++kk) {
        __syncthreads();
        if (kk + 1 < NK) stage(kk + 1, (kk + 1) & 1);
        const int buf = kk & 1;
        bf16x8 af[2], bfv[4];
        #pragma unroll
        for (int mi = 0; mi < 2; ++mi)
            af[mi] = *(const bf16x8*)&Ab[buf][(wm * 32 + mi * 16 + lr) * 32 + qd * 8];
        #pragma unroll
        for (int nt = 0; nt < 4; ++nt)
            bfv[nt] = *(const bf16x8*)&Bb[buf][(wn * 64 + nt * 16 + lr) * 32 + qd * 8];
        #pragma unroll
        for (int mi = 0; mi < 2; ++mi)
            #pragma unroll
            for (int nt = 0; nt < 4; ++nt)
                acc[mi][nt] = __builtin_amdgcn_mfma_f32_16x16x32_bf16(
                    af[mi], bfv[nt], acc[mi][nt], 0, 0, 0);
    }

    const int twoL = L << 1;
    #pragma unroll
    for (int nt = 0; nt < 4; ++nt) {
        const int col = wn * 64 + nt * 16 + lr;
        #pragma unroll
        for (int mi = 0; mi < 2; ++mi) {
            #pragma unroll
            for (int r = 0; r < 4; ++r) {
                const int row = mt * 64 + wm * 32 + mi * 16 + qd * 4 + r;
                const size_t gi = ((size_t)b * twoL + row) * 128 + col;
                float v = xh[gi] + sign * acc[mi][nt][r];
                out[gi] = v;
                if (xtm)
                    xtm[((size_t)b * 128 + col) * twoL + row] = f2bf(v);
            }
        }
    }
}

// up2_dec: all three decomposition GEMMs in ONE dispatch (was 3).
__global__ __launch_bounds__(256) void up2_dec(
    const unsigned short* __restrict__ U64p, const unsigned short* __restrict__ U128,
    const unsigned short* __restrict__ U256,
    const unsigned short* __restrict__ Xt3, const unsigned short* __restrict__ Xt2,
    const unsigned short* __restrict__ Xt1,
    const float* __restrict__ x2, const float* __restrict__ x1,
    const float* __restrict__ x0,
    float* __restrict__ d2, float* __restrict__ d1, float* __restrict__ d0)
{
    const int bid = blockIdx.x;
    const unsigned short *U, *Xt; const float* xh; float* out;
    int L, lgMT, base;
    if (bid < 256)      { U = U64p; Xt = Xt3; xh = x2; out = d2; L = 64;  lgMT = 1; base = 0; }
    else if (bid < 768) { U = U128; Xt = Xt2; xh = x1; out = d1; L = 128; lgMT = 2; base = 256; }
    else                { U = U256; Xt = Xt1; xh = x0; out = d0; L = 256; lgMT = 3; base = 768; }
    const int rb = bid - base;
    up2_body(U, Xt, xh, out, nullptr, -1.f, rb >> lgMT, rb & ((1 << lgMT) - 1), L);
}

// up2_mix: one mix-chain up-add (in-place), optional Xtm emit for next level.
__global__ __launch_bounds__(256) void up2_mix(
    const unsigned short* __restrict__ U, const unsigned short* __restrict__ Xt,
    float* __restrict__ m, unsigned short* __restrict__ xtm, int L, int lgMT)
{
    up2_body(U, Xt, m, m, xtm, 1.f,
             blockIdx.x >> lgMT, blockIdx.x & ((1 << lgMT) - 1), L);
}

// ---------------------------------------------------------------------------
// mkan_all: ALL FOUR mkan levels in one dispatch, prep_T fused in-LDS.
// Per block: 32(M) x 128(N) tile, K = deg1m1*128. Chebyshev planes
// T_1..T_deg1m1 built from x in LDS (bf16), so the Tw global round-trip
// (~134 MB in R4) is gone. 4 waves 1x(2x2): wave = 16 rows x 64 cols.
// LDS: As 32 KB (4 planes x 32x128) + Bb 16 KB = 48 KB -> 3 blocks/CU.
// Level-0 epilogue also writes Xtm0 (bf16 transposed m0).
// ---------------------------------------------------------------------------
__global__ __launch_bounds__(256) void mkan_all(
    const float* __restrict__ xa, const float* __restrict__ xb,
    const float* __restrict__ xc, const float* __restrict__ xd,
    const unsigned short* __restrict__ BmT_all,
    const float* __restrict__ bias_all,
    const float* __restrict__ w0p, const float* __restrict__ w1p,
    const float* __restrict__ w2p, const float* __restrict__ w3p,
    float* __restrict__ m0, float* __restrict__ m1,
    float* __restrict__ m2, float* __restrict__ m3,
    unsigned short* __restrict__ xtm0)
{
    __shared__ unsigned short As[16384];     // [kk-chunk][row*32 + (i&31)]
    __shared__ unsigned short Bb[2][4096];

    const int bid = blockIdx.x, tid = threadIdx.x;
    const float *x, *w; float* outp; unsigned short* xtm = nullptr;
    int set, mb, Lmask;
    if (bid < 256)       { x = xa; w = w0p; outp = m0; set = 0; mb = bid << 5;          Lmask = 63;  xtm = xtm0; }
    else if (bid < 768)  { x = xb; w = w1p; outp = m1; set = 1; mb = (bid - 256) << 5;  Lmask = 127; }
    else if (bid < 1792) { x = xc; w = w2p; outp = m2; set = 2; mb = (bid - 768) << 5;  Lmask = 255; }
    else                 { x = xd; w = w3p; outp = m3; set = 3; mb = (bid - 1792) << 5; Lmask = 511; }
    const int deg1m1 = set + 1;
    const int NK = deg1m1 << 2;
    const unsigned short* Bm = BmT_all + (size_t)set * 65536;
    const float* bias = bias_all + (set << 7);

    // ---- fused prep: u = tanh(tanh(x)); bf16 T-planes into As ----
    for (int e = tid * 4; e < 4096; e += 1024) {
        const int row = e >> 7, i = e & 127;
        float4 v = *(const float4*)(x + ((size_t)(mb + row)) * 128 + i);
        float u0 = tanhf(tanhf(v.x)), u1 = tanhf(tanhf(v.y));
        float u2 = tanhf(tanhf(v.z)), u3 = tanhf(tanhf(v.w));
        float tp0 = 1.f, tp1 = 1.f, tp2 = 1.f, tp3 = 1.f;
        float tc0 = u0, tc1 = u1, tc2 = u2, tc3 = u3;
        unsigned short* ap0 = &As[((i >> 5) << 10) + (row << 5) + (i & 31)];
        for (int p = 0; p < deg1m1; ++p) {
            unsigned short* ap = ap0 + (p << 12);
            ap[0] = f2bf(tc0); ap[1] = f2bf(tc1);
            ap[2] = f2bf(tc2); ap[3] = f2bf(tc3);
            float tn0 = fmaf(2.f * u0, tc0, -tp0); tp0 = tc0; tc0 = tn0;
            float tn1 = fmaf(2.f * u1, tc1, -tp1); tp1 = tc1; tc1 = tn1;
            float tn2 = fmaf(2.f * u2, tc2, -tp2); tp2 = tc2; tc2 = tn2;
            float tn3 = fmaf(2.f * u3, tc3, -tp3); tp3 = tc3; tc3 = tn3;
        }
    }

    const int ln = tid & 63, wv = tid >> 6;
    const int wm = wv & 1, wn = wv >> 1;
    const int lr = ln & 15, qd = ln >> 4;

    f32x4 acc[4];
    #pragma unroll
    for (int nt = 0; nt < 4; ++nt) acc[nt] = (f32x4){0.f, 0.f, 0.f, 0.f};

    auto stageB = [&](int kk, int buf) {
        const int p = kk >> 2, i0 = (kk & 3) << 5;
        #pragma unroll
        for (int j = 0; j < 2; ++j) {
            int sidx = tid + (j << 8);
            const unsigned short* gb =
                Bm + (size_t)((p << 7) + (sidx >> 2)) * 128 + i0 + ((sidx & 3) << 3);
            ((bf16x8*)Bb[buf])[sidx] = *(const bf16x8*)gb;
        }
    };

    stageB(0, 0);
    for (int kk = 0; kk < NK; ++kk) {
        __syncthreads();                     // covers As prep (kk=0) + Bb[buf]
        if (kk + 1 < NK) stageB(kk + 1, (kk + 1) & 1);
        const int buf = kk & 1;
        bf16x8 af = *(const bf16x8*)&As[(kk << 10) + (((wm << 4) + lr) << 5) + (qd << 3)];
        bf16x8 bfv[4];
        #pragma unroll
        for (int nt = 0; nt < 4; ++nt)
            bfv[nt] = *(const bf16x8*)&Bb[buf][(((wn << 6) + (nt << 4) + lr) << 5) + (qd << 3)];
        #pragma unroll
        for (int nt = 0; nt < 4; ++nt)
            acc[nt] = __builtin_amdgcn_mfma_f32_16x16x32_bf16(af, bfv[nt], acc[nt], 0, 0, 0);
    }

    // epilogue: bias + depthwise conv3 (+ optional bf16-T copy for level 0)
    #pragma unroll
    for (int nt = 0; nt < 4; ++nt) {
        const int col = (wn << 6) + (nt << 4) + lr;
        const float ww0 = w[col * 3 + 0], ww1 = w[col * 3 + 1], ww2 = w[col * 3 + 2];
        const float bs = bias[col];
        #pragma unroll
        for (int r = 0; r < 4; ++r) {
            const int row = (wm << 4) + (qd << 2) + r;
            const int gm = mb + row;
            const int n = gm & Lmask;
            const size_t gi = (size_t)gm * 128 + col;
            float xm1 = (n > 0)     ? x[gi - 128] : 0.f;
            float x0v = x[gi];
            float xp1 = (n < Lmask) ? x[gi + 128] : 0.f;
            float v = acc[nt][r] + bs + fmaf(ww0, xm1, fmaf(ww1, x0v, ww2 * xp1));
            outp[gi] = v;
            if (xtm)
                xtm[(size_t)(((gm >> 6) << 7) + col) * 64 + (gm & 63)] = f2bf(v);
        }
    }
}

// ---------------------------------------------------------------------------
extern "C" void kernel_launch(void* const* d_in, const int* in_sizes, int n_in,
                              void* d_out, int out_size, void* d_ws, size_t ws_size,
                              hipStream_t stream) {
    const float* x0 = (const float*)d_in[0];
    const float* x1 = (const float*)d_in[1];
    const float* x2 = (const float*)d_in[2];
    const float* x3 = (const float*)d_in[3];
    const float* c0 = (const float*)d_in[4];
    const float* w0 = (const float*)d_in[5];
    const float* c1 = (const float*)d_in[6];
    const float* w1 = (const float*)d_in[7];
    const float* c2 = (const float*)d_in[8];
    const float* w2 = (const float*)d_in[9];
    const float* c3 = (const float*)d_in[10];
    const float* w3 = (const float*)d_in[11];
    float* out = (float*)d_out;

    // ws: d0|d1|d2 (56MB) + Xt1..3 + Xtm0..2 (29MB) + BmT + bias + U (~0.9MB)
    float* d0 = (float*)d_ws;                               // 8388608 f
    float* d1 = d0 + 8388608;                               // 4194304 f
    float* d2 = d1 + 4194304;                               // 2097152 f
    unsigned short* Xt1  = (unsigned short*)(d2 + 2097152); // 4194304 us
    unsigned short* Xt2  = Xt1 + 4194304;                   // 2097152
    unsigned short* Xt3  = Xt2 + 2097152;                   // 1048576
    unsigned short* Xtm0 = Xt3 + 1048576;                   // 1048576
    unsigned short* Xtm1 = Xtm0 + 1048576;                  // 2097152
    unsigned short* Xtm2 = Xtm1 + 2097152;                  // 4194304
    unsigned short* BmT  = Xtm2 + 4194304;                  // 262144
    float* bias_all = (float*)(BmT + 262144);               // 512 f
    unsigned short* U256 = (unsigned short*)(bias_all + 512);
    unsigned short* U128 = U256 + 131072;
    unsigned short* U64p = U128 + 32768;                    // 8192

    float* m3 = out;                                        // (128,512,128)
    float* m2 = m3 + 8388608;                               // (128,256,128)
    float* m1 = m2 + 4194304;                               // (128,128,128)
    float* m0 = m1 + 2097152;                               // (128, 64,128)

    // 6 dispatches total (was ~25 — gaps dominated R4's wall time)
    prep_all<<<1824, 256, 0, stream>>>(x1, x2, x3, Xt1, Xt2, Xt3,
                                       U256, U128, U64p,
                                       c0, c1, c2, c3, BmT, bias_all);

    up2_dec<<<1792, 256, 0, stream>>>(U64p, U128, U256, Xt3, Xt2, Xt1,
                                      x2, x1, x0, d2, d1, d0);

    mkan_all<<<3840, 256, 0, stream>>>(x3, d2, d1, d0, BmT, bias_all,
                                       w0, w1, w2, w3, m0, m1, m2, m3, Xtm0);

    up2_mix<<<256,  256, 0, stream>>>(U64p, Xtm0, m1, Xtm1, 64, 1);
    up2_mix<<<512,  256, 0, stream>>>(U128, Xtm1, m2, Xtm2, 128, 2);
    up2_mix<<<1024, 256, 0, stream>>>(U256, Xtm2, m3, nullptr, 256, 3);
}